// Round 1
// baseline (36233.078 us; speedup 1.0000x reference)
//
#include <hip/hip_runtime.h>
#include <cstdint>
#include <cstddef>

#define NNODE 118
#define TSEQ  2048
#define NEGC  -1000000000.0f

typedef __fp16 h2v __attribute__((ext_vector_type(2)));

__device__ __forceinline__ float leakyf(float x){ return x >= 0.f ? x : 0.01f * x; }
__device__ __forceinline__ float sigm(float x){ return 1.f / (1.f + __expf(-x)); }
__device__ __forceinline__ float tanhfast(float x){ float e = __expf(2.f * x); return 1.f - 2.f / (e + 1.f); }

__device__ __forceinline__ float fdot2(h2v a, h2v b, float c){
#if __has_builtin(__builtin_amdgcn_fdot2)
  return __builtin_amdgcn_fdot2(a, b, c, false);
#else
  return c + (float)a.x * (float)b.x + (float)a.y * (float)b.y;
#endif
}

// generic block reductions (nthr = blockDim.x, power of two)
__device__ float bred_sum(float v, float* buf, int nthr){
  int tid = threadIdx.x;
  buf[tid] = v; __syncthreads();
  for (int s = nthr >> 1; s > 0; s >>= 1){
    if (tid < s) buf[tid] += buf[tid + s];
    __syncthreads();
  }
  float r = buf[0]; __syncthreads(); return r;
}
__device__ float bred_max(float v, float* buf, int nthr){
  int tid = threadIdx.x;
  buf[tid] = v; __syncthreads();
  for (int s = nthr >> 1; s > 0; s >>= 1){
    if (tid < s) buf[tid] = fmaxf(buf[tid], buf[tid + s]);
    __syncthreads();
  }
  float r = buf[0]; __syncthreads(); return r;
}

// ---------------- K0: fp32 -> fp16 convert (vectorized) ----------------
__global__ void f32_to_f16(const float4* __restrict__ in, uint2* __restrict__ out, int n4){
  int i = blockIdx.x * blockDim.x + threadIdx.x;
  int stride = gridDim.x * blockDim.x;
  for (; i < n4; i += stride){
    float4 v = in[i];
    h2v a; a.x = (__fp16)v.x; a.y = (__fp16)v.y;
    h2v b; b.x = (__fp16)v.z; b.y = (__fp16)v.w;
    uint2 o;
    o.x = __builtin_bit_cast(unsigned int, a);
    o.y = __builtin_bit_cast(unsigned int, b);
    out[i] = o;
  }
}

// ---------------- LSTM scan: one block per node, 512 threads ----------------
// thread t owns gate row t. Weights in VGPRs (packed fp16), h/x broadcast via LDS.
__global__ __launch_bounds__(512, 2) void lstm_scan(
    const unsigned int* __restrict__ xin,   // [NNODE][TSEQ][64] uints (128 halves)
    const float* __restrict__ W_ih,         // [512][128]
    const float* __restrict__ W_hh,         // [512][128]
    const float* __restrict__ b_ih,
    const float* __restrict__ b_hh,
    unsigned int* __restrict__ hout,        // [NNODE][TSEQ][64] uints, or null
    float* __restrict__ pout)               // [NNODE][128] leaky(final h), or null
{
  const int n = blockIdx.x, tid = threadIdx.x;
  __shared__ unsigned int lds_x[64];
  __shared__ unsigned int lds_h[64];
  __shared__ float lds_g[512];

  h2v wih[64], whh[64];
  {
    const float2* wi2 = (const float2*)(W_ih + (size_t)tid * 128);
    const float2* wh2 = (const float2*)(W_hh + (size_t)tid * 128);
    #pragma unroll 8
    for (int k = 0; k < 64; k++){ float2 a = wi2[k]; h2v v; v.x = (__fp16)a.x; v.y = (__fp16)a.y; wih[k] = v; }
    #pragma unroll 8
    for (int k = 0; k < 64; k++){ float2 a = wh2[k]; h2v v; v.x = (__fp16)a.x; v.y = (__fp16)a.y; whh[k] = v; }
  }
  const float bias = b_ih[tid] + b_hh[tid];
  float c = 0.f;
  if (tid < 64) lds_h[tid] = 0u;

  const unsigned int* xb = xin + (size_t)n * TSEQ * 64;
  unsigned int px = 0;
  if (tid < 64) px = xb[tid];

  for (int t = 0; t < TSEQ; t++){
    if (tid < 64) lds_x[tid] = px;
    __syncthreads();                         // h(t-1) and x(t) visible
    if (tid < 64 && t + 1 < TSEQ) px = xb[(size_t)(t + 1) * 64 + tid];

    float acc = bias;
    const h2v* x2 = (const h2v*)lds_x;
    const h2v* h2 = (const h2v*)lds_h;
    #pragma unroll
    for (int k = 0; k < 64; k++) acc = fdot2(wih[k], x2[k], acc);
    #pragma unroll
    for (int k = 0; k < 64; k++) acc = fdot2(whh[k], h2[k], acc);
    lds_g[tid] = acc;
    __syncthreads();                         // all gates ready

    if (tid < 128){
      float gi = lds_g[tid], gf = lds_g[tid + 128], gg = lds_g[tid + 256], go = lds_g[tid + 384];
      c = sigm(gf) * c + sigm(gi) * tanhfast(gg);
      float hv = sigm(go) * tanhfast(c);
      ((__fp16*)lds_h)[tid] = (__fp16)hv;
      if (hout) ((__fp16*)hout)[(size_t)n * TSEQ * 128 + (size_t)t * 128 + tid] = (__fp16)hv;
      if (pout && t == TSEQ - 1) pout[n * 128 + tid] = leakyf(hv);
    }
    // next loop-top __syncthreads orders lds_h writes vs. next gate reads
  }
}

// ---------------- H1: per-node MLP up to n ----------------
__global__ void node_mlp(
    const float* __restrict__ x_tag,   // [118][3]
    const float* __restrict__ pm,      // [768]
    const float* __restrict__ Wvm,     // [769][128]
    const float* __restrict__ Wup,     // [128][128]
    const float* __restrict__ W_hyb,   // [384][256]
    const float* __restrict__ b_hyb,   // [256]
    const float* __restrict__ W_act,   // [258][256]
    const float* __restrict__ b_act,   // [256]
    const float* __restrict__ W_inact, // [256][256]
    const float* __restrict__ b_inact, // [256]
    const float* __restrict__ p,       // [118][128]
    float* __restrict__ nmat)          // [118][256]
{
  int n = blockIdx.x, tid = threadIdx.x;
  __shared__ float pl[128], up[128], vm[128], hh[256];
  float act = x_tag[n * 3 + 2], hp0 = x_tag[n * 3 + 0], hp1 = x_tag[n * 3 + 1];
  if (tid < 128) pl[tid] = p[n * 128 + tid];
  __syncthreads();
  if (tid < 128){
    float a1 = 0.f;
    for (int k = 0; k < 768; k++) a1 += pm[k] * Wvm[k * 128 + tid];
    a1 += act * Wvm[768 * 128 + tid];
    vm[tid] = leakyf(a1);
    float a2 = 0.f;
    for (int k = 0; k < 128; k++) a2 += pl[k] * Wup[k * 128 + tid];
    up[tid] = leakyf(a2);
  }
  __syncthreads();
  {
    float a = b_hyb[tid];
    for (int k = 0; k < 128; k++) a += up[k] * W_hyb[k * 256 + tid];
    for (int k = 0; k < 128; k++) a += (up[k] + vm[k]) * W_hyb[(128 + k) * 256 + tid];
    for (int k = 0; k < 128; k++) a += vm[k] * W_hyb[(256 + k) * 256 + tid];
    hh[tid] = leakyf(a);
  }
  __syncthreads();
  {
    float na = b_act[tid];
    for (int k = 0; k < 256; k++) na += hh[k] * W_act[k * 256 + tid];
    na += hp0 * W_act[256 * 256 + tid] + hp1 * W_act[257 * 256 + tid];
    float ni = b_inact[tid];
    for (int k = 0; k < 256; k++) ni += hh[k] * W_inact[k * 256 + tid];
    nmat[n * 256 + tid] = leakyf(na * (1.f - act) + ni * act);
  }
}

// ---------------- H2: per-node projections of n ----------------
__global__ void node_proj(
    const float* __restrict__ nmat,
    const float* __restrict__ Wphin,   // [512][192]
    const float* __restrict__ Won,     // [512][256]
    const float* __restrict__ Weo,     // [768][256]
    float* __restrict__ A, float* __restrict__ B,     // [118][192]
    float* __restrict__ C, float* __restrict__ D,     // [118][256]
    float* __restrict__ Q, float* __restrict__ R)     // [118][256]
{
  int n = blockIdx.x, tid = threadIdx.x;
  __shared__ float nl[256];
  nl[tid] = nmat[n * 256 + tid];
  __syncthreads();
  if (tid < 192){
    float a = 0.f, b = 0.f;
    for (int k = 0; k < 256; k++){ float v = nl[k]; a += v * Wphin[k * 192 + tid]; b += v * Wphin[(256 + k) * 192 + tid]; }
    A[n * 192 + tid] = a; B[n * 192 + tid] = b;
  }
  float c = 0.f, d = 0.f, q = 0.f, r = 0.f;
  for (int k = 0; k < 256; k++){
    float v = nl[k];
    c += v * Won[k * 256 + tid];
    d += v * Won[(256 + k) * 256 + tid];
    q += v * Weo[(256 + k) * 256 + tid];
    r += v * Weo[(512 + k) * 256 + tid];
  }
  C[n * 256 + tid] = c; D[n * 256 + tid] = d;
  Q[n * 256 + tid] = q; R[n * 256 + tid] = r;
}

// ---------------- H3: phi[i,j] = sum_k leaky(A[j,k]+B[i,k]) aphi[k] ----------------
// block = column j, thread = row i; store phiT[j][i]
__global__ void phi_kernel(const float* __restrict__ A, const float* __restrict__ B,
                           const float* __restrict__ aphi, float* __restrict__ phiT)
{
  int j = blockIdx.x, tid = threadIdx.x;
  __shared__ float Aj[192], ap[192];
  for (int k = tid; k < 192; k += 128){ Aj[k] = A[j * 192 + k]; ap[k] = aphi[k]; }
  __syncthreads();
  if (tid < NNODE){
    const float* Bi = B + (size_t)tid * 192;
    float s = 0.f;
    for (int k = 0; k < 192; k++) s += leakyf(Aj[k] + Bi[k]) * ap[k];
    phiT[j * NNODE + tid] = s;
  }
}

// ---------------- H4: masked softmaxes over axis 0 (rows i), per column j ----------------
__global__ void alpha_kernel(const float* __restrict__ phiT, const float* __restrict__ x_tag,
                             float* __restrict__ alpha)
{
  int j = blockIdx.x, tid = threadIdx.x;
  __shared__ float buf[128];
  bool valid = tid < NNODE;
  float ph = valid ? phiT[j * NNODE + tid] : 0.f;
  float a  = valid ? x_tag[tid * 3 + 2] : -1.f;
  bool v1 = (a == 0.f), v0 = (a == 1.f);

  float c1 = bred_sum((valid && v1) ? 1.f : 0.f, buf, 128);

  float x1 = (valid && v1) ? ph : NEGC;
  float m1 = bred_max(valid ? x1 : -3.4e38f, buf, 128);
  float e1 = valid ? __expf(x1 - m1) : 0.f;
  float s1 = bred_sum(e1, buf, 128);
  float p1 = e1 / s1;

  float x0 = (valid && v0) ? ph : NEGC;
  float m0 = bred_max(valid ? x0 : -3.4e38f, buf, 128);
  float e0 = valid ? __expf(x0 - m0) : 0.f;
  float s0 = bred_sum(e0, buf, 128);
  float p0 = e0 / s0;

  float ma = bred_max(valid ? ph : -3.4e38f, buf, 128);
  float ea = valid ? __expf(ph - ma) : 0.f;
  float sa = bred_sum(ea, buf, 128);
  float pa = ea / sa;

  float pmask = v1 ? p1 : (v0 ? p0 : ph);
  float al = (c1 > 0.f) ? pmask : pa;
  if (valid) alpha[tid * NNODE + j] = al;
}

// ---------------- H5: alpha-weighted sums ----------------
__global__ void att_sum(const float* __restrict__ alpha, const float* __restrict__ C,
                        const float* __restrict__ D, const float* __restrict__ Q,
                        const float* __restrict__ R, const float* __restrict__ nmat,
                        float* __restrict__ T1, float* __restrict__ Spart,
                        float* __restrict__ nrm)
{
  int i = blockIdx.x, tid = threadIdx.x;
  __shared__ float al[128];
  __shared__ float rb[256];
  if (tid < 128) al[tid] = (tid < NNODE) ? alpha[i * NNODE + tid] : 0.f;
  __syncthreads();
  float Di = D[i * 256 + tid];
  float acc1 = 0.f, acc2 = 0.f, sa = 0.f;
  for (int jj = 0; jj < NNODE; jj++){
    float av = al[jj]; sa += av;
    acc1 += av * leakyf(C[jj * 256 + tid] + Di);
    acc2 += av * Q[jj * 256 + tid];
  }
  T1[i * 256 + tid] = acc1;
  Spart[i * 256 + tid] = acc2 + sa * R[i * 256 + tid];
  float nv = nmat[i * 256 + tid];
  float ss = bred_sum(nv * nv, rb, 256);
  if (tid == 0) nrm[i] = fmaxf(sqrtf(ss), 1e-8f);
}

// ---------------- H6: per-node finalize: S, hyper_m, y_hat, outputs, l_pol vec ----------------
__global__ void finalize_node(const float* __restrict__ T1, const float* __restrict__ Spart,
                              const float* __restrict__ Weo, const float* __restrict__ nmat,
                              const float* __restrict__ x_tag, const float* __restrict__ Wi,
                              const float* __restrict__ bi, const float* __restrict__ nrm,
                              float* __restrict__ vvec, float* __restrict__ out)
{
  int i = blockIdx.x, tid = threadIdx.x;
  __shared__ float t1[256];
  __shared__ float rb[256];
  t1[tid] = T1[i * 256 + tid];
  __syncthreads();
  float s = Spart[i * 256 + tid];
  for (int k = 0; k < 256; k++) s += t1[k] * Weo[k * 256 + tid];
  float act = x_tag[i * 3 + 2], hp0 = x_tag[i * 3 + 0], hp1 = x_tag[i * 3 + 1];
  float hm0 = leakyf(act * s);
  float hm1 = leakyf((1.f - act) * s);
  float nd = nmat[i * 256 + tid];
  const float* Wir = Wi + (size_t)i * 1536;
  float y0 = nd * Wir[tid * 2]     + hm0 * Wir[(256 + tid) * 2]     + hm1 * Wir[(512 + tid) * 2];
  float y1 = nd * Wir[tid * 2 + 1] + hm0 * Wir[(256 + tid) * 2 + 1] + hm1 * Wir[(512 + tid) * 2 + 1];
  y0 = bred_sum(y0, rb, 256);
  y1 = bred_sum(y1, rb, 256);
  // l_pol vector contribution: v += s_i * n_i / ||n_i||
  float sgn = (hp1 > hp0) ? 1.f : ((hp1 < hp0) ? -1.f : 0.f);
  if (act == 0.f && sgn != 0.f) atomicAdd(vvec + tid, sgn * nd / nrm[i]);
  if (tid == 0){
    y0 += bi[i * 2]; y1 += bi[i * 2 + 1];
    float m = fmaxf(y0, y1);
    float ee0 = __expf(y0 - m), ee1 = __expf(y1 - m);
    float ssum = ee0 + ee1;
    out[i * 2]     = ee0 / ssum;
    out[i * 2 + 1] = ee1 / ssum;
    out[236 + i * 2]     = hp0;
    out[236 + i * 2 + 1] = hp1;
    out[474 + i] = (act == 0.f) ? 1.f : 0.f;
    out[592 + i] = (act == 1.f) ? 1.f : 0.f;
  }
}

// ---------------- H_ort: l_ort via trace trick ----------------
__global__ void ort_kernel(const float* __restrict__ Wum, const float* __restrict__ Wvm,
                           const float* __restrict__ Wup, const float* __restrict__ Wvp,
                           float* __restrict__ misc)
{
  int a = blockIdx.x, b = threadIdx.x;
  float g1 = 0.f, g2 = 0.f, g3 = 0.f, g4 = 0.f;
  for (int r = 0; r < 769; r++){
    g1 += Wum[r * 128 + a] * Wum[r * 128 + b];
    g2 += Wvm[r * 128 + a] * Wvm[r * 128 + b];
  }
  for (int r = 0; r < 128; r++){
    g3 += Wup[r * 128 + a] * Wup[r * 128 + b];
    g4 += Wvp[r * 128 + a] * Wvp[r * 128 + b];
  }
  __shared__ float rb[128];
  float s1 = bred_sum(g1 * g2, rb, 128);
  float s2 = bred_sum(g3 * g4, rb, 128);
  if (b == 0){ atomicAdd(misc + 0, s1); atomicAdd(misc + 1, s2); }
}

// ---------------- H7: scalars ----------------
__global__ void finalize_scalars(const float* __restrict__ misc, const float* __restrict__ vvec,
                                 float* __restrict__ out)
{
  __shared__ float rb[256];
  int tid = threadIdx.x;
  float v = vvec[tid];
  float ss = bred_sum(v * v, rb, 256);
  if (tid == 0){
    out[472] = sqrtf(misc[0]) + sqrtf(misc[1]);
    out[473] = ss;
  }
}

extern "C" void kernel_launch(void* const* d_in, const int* in_sizes, int n_in,
                              void* d_out, int out_size, void* d_ws, size_t ws_size,
                              hipStream_t stream)
{
  const float* x        = (const float*)d_in[0];
  const float* x_tag    = (const float*)d_in[1];
  const float* W_ih0    = (const float*)d_in[2];
  const float* W_hh0    = (const float*)d_in[3];
  const float* b_ih0    = (const float*)d_in[4];
  const float* b_hh0    = (const float*)d_in[5];
  const float* W_ih1    = (const float*)d_in[6];
  const float* W_hh1    = (const float*)d_in[7];
  const float* b_ih1    = (const float*)d_in[8];
  const float* b_hh1    = (const float*)d_in[9];
  const float* pm       = (const float*)d_in[10];
  const float* Wum      = (const float*)d_in[11];
  const float* Wvm      = (const float*)d_in[12];
  const float* Wup      = (const float*)d_in[13];
  const float* Wvp      = (const float*)d_in[14];
  const float* W_hyb    = (const float*)d_in[15];
  const float* b_hyb    = (const float*)d_in[16];
  const float* W_act    = (const float*)d_in[17];
  const float* b_act    = (const float*)d_in[18];
  const float* W_inact  = (const float*)d_in[19];
  const float* b_inact  = (const float*)d_in[20];
  const float* Wphin    = (const float*)d_in[21];
  const float* aphi     = (const float*)d_in[22];
  const float* Won      = (const float*)d_in[23];
  const float* Weo      = (const float*)d_in[24];
  const float* Wi       = (const float*)d_in[25];
  const float* bi       = (const float*)d_in[26];
  float* out = (float*)d_out;

  char* base = (char*)d_ws;
  size_t off = 0;
  auto take = [&](size_t bytes) -> char* {
    char* p = base + off;
    off += (bytes + 255) & ~(size_t)255;
    return p;
  };
  const size_t seq_halves = (size_t)NNODE * TSEQ * 128;       // 30,932,992
  unsigned int* x16  = (unsigned int*)take(seq_halves * 2);
  unsigned int* h1b  = (unsigned int*)take(seq_halves * 2);
  float* pbuf  = (float*)take((size_t)NNODE * 128 * 4);
  float* nmat  = (float*)take((size_t)NNODE * 256 * 4);
  float* Amat  = (float*)take((size_t)NNODE * 192 * 4);
  float* Bmat  = (float*)take((size_t)NNODE * 192 * 4);
  float* Cmat  = (float*)take((size_t)NNODE * 256 * 4);
  float* Dmat  = (float*)take((size_t)NNODE * 256 * 4);
  float* Qmat  = (float*)take((size_t)NNODE * 256 * 4);
  float* Rmat  = (float*)take((size_t)NNODE * 256 * 4);
  float* phiT  = (float*)take((size_t)NNODE * NNODE * 4);
  float* alpha = (float*)take((size_t)NNODE * NNODE * 4);
  float* T1    = (float*)take((size_t)NNODE * 256 * 4);
  float* Spart = (float*)take((size_t)NNODE * 256 * 4);
  float* nrm   = (float*)take((size_t)NNODE * 4);
  float* vvec  = (float*)take(256 * 4);          // 1024B, misc follows contiguously
  float* misc  = (float*)take(8 * 4);

  // zero the atomic accumulators (vvec 1024B padded, then misc)
  hipMemsetAsync(vvec, 0, 1024 + 32, stream);

  // convert x to fp16
  int n4 = (int)(seq_halves / 4);
  f32_to_f16<<<8192, 256, 0, stream>>>((const float4*)x, (uint2*)x16, n4);

  // LSTM layer 1: writes h1 sequence (fp16)
  lstm_scan<<<NNODE, 512, 0, stream>>>(x16, W_ih0, W_hh0, b_ih0, b_hh0, h1b, nullptr);
  // LSTM layer 2: writes p = leaky(final h)
  lstm_scan<<<NNODE, 512, 0, stream>>>(h1b, W_ih1, W_hh1, b_ih1, b_hh1, nullptr, pbuf);

  node_mlp<<<NNODE, 256, 0, stream>>>(x_tag, pm, Wvm, Wup, W_hyb, b_hyb,
                                      W_act, b_act, W_inact, b_inact, pbuf, nmat);
  node_proj<<<NNODE, 256, 0, stream>>>(nmat, Wphin, Won, Weo, Amat, Bmat, Cmat, Dmat, Qmat, Rmat);
  phi_kernel<<<NNODE, 128, 0, stream>>>(Amat, Bmat, aphi, phiT);
  alpha_kernel<<<NNODE, 128, 0, stream>>>(phiT, x_tag, alpha);
  att_sum<<<NNODE, 256, 0, stream>>>(alpha, Cmat, Dmat, Qmat, Rmat, nmat, T1, Spart, nrm);
  finalize_node<<<NNODE, 256, 0, stream>>>(T1, Spart, Weo, nmat, x_tag, Wi, bi, nrm, vvec, out);
  ort_kernel<<<128, 128, 0, stream>>>(Wum, Wvm, Wup, Wvp, misc);
  finalize_scalars<<<1, 256, 0, stream>>>(misc, vvec, out);
}

// Round 2
// 4160.537 us; speedup vs baseline: 8.7087x; 8.7087x over previous
//
#include <hip/hip_runtime.h>
#include <cstdint>
#include <cstddef>

#define NNODE 118
#define TSEQ  2048
#define TC    256          // chunk length (TSEQ/8)
#define NCH   8
#define NEGC  -1000000000.0f

typedef __fp16 h2v __attribute__((ext_vector_type(2)));
typedef short short8 __attribute__((ext_vector_type(8)));
typedef float floatx4 __attribute__((ext_vector_type(4)));

__device__ __forceinline__ float leakyf(float x){ return x >= 0.f ? x : 0.01f * x; }
__device__ __forceinline__ float sigm(float x){ return 1.f / (1.f + __expf(-x)); }
__device__ __forceinline__ float tanhfast(float x){ float e = __expf(2.f * x); return 1.f - 2.f / (e + 1.f); }

__device__ __forceinline__ unsigned short bf16rne(float x){
  unsigned int u = __builtin_bit_cast(unsigned int, x);
  u = (u + 0x7fffu + ((u >> 16) & 1u)) >> 16;
  return (unsigned short)u;
}

__device__ __forceinline__ float fdot2(h2v a, h2v b, float c){
#if __has_builtin(__builtin_amdgcn_fdot2)
  return __builtin_amdgcn_fdot2(a, b, c, false);
#else
  return c + (float)a.x * (float)b.x + (float)a.y * (float)b.y;
#endif
}
__device__ __forceinline__ h2v bch2(unsigned int u){ return __builtin_bit_cast(h2v, u); }

__device__ float bred_sum(float v, float* buf, int nthr){
  int tid = threadIdx.x;
  buf[tid] = v; __syncthreads();
  for (int s = nthr >> 1; s > 0; s >>= 1){
    if (tid < s) buf[tid] += buf[tid + s];
    __syncthreads();
  }
  float r = buf[0]; __syncthreads(); return r;
}
__device__ float bred_max(float v, float* buf, int nthr){
  int tid = threadIdx.x;
  buf[tid] = v; __syncthreads();
  for (int s = nthr >> 1; s > 0; s >>= 1){
    if (tid < s) buf[tid] = fmaxf(buf[tid], buf[tid + s]);
    __syncthreads();
  }
  float r = buf[0]; __syncthreads(); return r;
}

// ---------------- convert f32 -> bf16 (for W_ih matrices) ----------------
__global__ void f32_to_bf16_k(const float* __restrict__ in, unsigned short* __restrict__ out, int n){
  int i = blockIdx.x * blockDim.x + threadIdx.x;
  if (i < n) out[i] = bf16rne(in[i]);
}

// ---------------- pre-gate GEMM: pre[m, g] = sum_k A[m,k] * W[g,k] (bf16 MFMA) ----------------
// A: rows m = n*TSEQ + t0 + tb*64 + wave*16 + (lane&15), K=128. Grid: 472 blocks (118 nodes x 4), 256 thr.
__global__ __launch_bounds__(256, 4) void pregemm(
    const void* __restrict__ Aptr, int a_f32,
    const unsigned short* __restrict__ Wb,   // bf16 [512][128]
    __fp16* __restrict__ pre,                // [NNODE*TC][512]
    int t0)
{
  const int tid = threadIdx.x, lane = tid & 63, wv = tid >> 6;
  const int blk = blockIdx.x;
  const int n = blk >> 2, tb = blk & 3;
  const int rbase_pre = n * TC + tb * 64 + wv * 16;
  const size_t rbase_gl = (size_t)n * TSEQ + t0 + tb * 64 + wv * 16;
  const int r16 = lane & 15, kq = lane >> 4;
  __shared__ __fp16 lds[4][16 * 132];

  short8 af[4];
  if (a_f32){
    const float* A = (const float*)Aptr;
    #pragma unroll
    for (int kt = 0; kt < 4; kt++){
      const float* p = A + (rbase_gl + r16) * 128 + kt * 32 + kq * 8;
      float4 x0 = ((const float4*)p)[0];
      float4 x1 = ((const float4*)p)[1];
      short8 s;
      s[0] = (short)bf16rne(x0.x); s[1] = (short)bf16rne(x0.y);
      s[2] = (short)bf16rne(x0.z); s[3] = (short)bf16rne(x0.w);
      s[4] = (short)bf16rne(x1.x); s[5] = (short)bf16rne(x1.y);
      s[6] = (short)bf16rne(x1.z); s[7] = (short)bf16rne(x1.w);
      af[kt] = s;
    }
  } else {
    const unsigned short* A = (const unsigned short*)Aptr;
    #pragma unroll
    for (int kt = 0; kt < 4; kt++){
      const unsigned short* p = A + (rbase_gl + r16) * 128 + kt * 32 + kq * 8;
      af[kt] = __builtin_bit_cast(short8, *(const uint4*)p);
    }
  }

  __fp16* lw = &lds[wv][0];
  for (int g8 = 0; g8 < 4; g8++){
    #pragma unroll
    for (int ntc = 0; ntc < 8; ntc++){
      int nt = g8 * 8 + ntc;
      floatx4 acc = {0.f, 0.f, 0.f, 0.f};
      #pragma unroll
      for (int kt = 0; kt < 4; kt++){
        const unsigned short* bp = Wb + (size_t)(nt * 16 + r16) * 128 + kt * 32 + kq * 8;
        short8 bfr = __builtin_bit_cast(short8, *(const uint4*)bp);
        acc = __builtin_amdgcn_mfma_f32_16x16x32_bf16(af[kt], bfr, acc, 0, 0, 0);
      }
      // C layout: col = lane&15, row = kq*4 + reg  -> transpose to row-major via LDS
      #pragma unroll
      for (int r = 0; r < 4; r++){
        int crow = kq * 4 + r, ccol = ntc * 16 + r16;
        lw[crow * 132 + ccol] = (__fp16)acc[r];
      }
    }
    // flush 16 rows x 128 cols (coalesced)
    #pragma unroll
    for (int i = 0; i < 4; i++){
      int r2 = i * 4 + kq, ch = r16;
      uint4 v = *(const uint4*)&lw[r2 * 132 + ch * 8];
      *(uint4*)(pre + ((size_t)(rbase_pre + r2)) * 512 + g8 * 128 + ch * 8) = v;
    }
  }
}

// ---------------- LSTM scan (chunked, pre-gates precomputed) ----------------
// 256 threads; thread owns gates 2t, 2t+1. W_hh rows in VGPRs (FULL unroll). h in LDS fp16.
__global__ __launch_bounds__(256, 2) void lstm_scan_pre(
    const __fp16* __restrict__ pre,      // [NNODE*TC][512]
    const float* __restrict__ W_hh,      // [512][128]
    const float* __restrict__ b_ih,
    const float* __restrict__ b_hh,
    unsigned short* __restrict__ hout,   // bf16 [NNODE][TSEQ][128] or null
    float* __restrict__ pout,            // [NNODE][128] or null (last chunk L2)
    unsigned int* __restrict__ h_state,  // fp16-pairs [NNODE][64]
    float* __restrict__ c_state,         // [NNODE][128]
    int t0)
{
  const int n = blockIdx.x, tid = threadIdx.x;
  __shared__ unsigned int lds_h[64];
  __shared__ float lds_g[512];

  const int g0 = tid * 2;
  h2v whA[64], whB[64];
  {
    const float2* wa = (const float2*)(W_hh + (size_t)g0 * 128);
    const float2* wb = (const float2*)(W_hh + (size_t)(g0 + 1) * 128);
    #pragma unroll
    for (int k = 0; k < 64; k++){ float2 v = wa[k]; h2v h; h.x = (__fp16)v.x; h.y = (__fp16)v.y; whA[k] = h; }
    #pragma unroll
    for (int k = 0; k < 64; k++){ float2 v = wb[k]; h2v h; h.x = (__fp16)v.x; h.y = (__fp16)v.y; whB[k] = h; }
  }
  const float biasA = b_ih[g0] + b_hh[g0];
  const float biasB = b_ih[g0 + 1] + b_hh[g0 + 1];

  float c = 0.f, hlast = 0.f;
  if (t0 == 0){
    if (tid < 64) lds_h[tid] = 0u;
  } else {
    if (tid < 64) lds_h[tid] = h_state[n * 64 + tid];
    if (tid < 128) c = c_state[n * 128 + tid];
  }
  const unsigned int* prow = (const unsigned int*)pre + (size_t)n * TC * 256;
  unsigned int pv = prow[tid];
  __syncthreads();

  for (int t = 0; t < TC; t++){
    unsigned int pvn = 0;
    if (t + 1 < TC) pvn = prow[(size_t)(t + 1) * 256 + tid];

    h2v pp = bch2(pv);
    float aA0 = (float)pp.x + biasA, aA1 = 0.f;
    float aB0 = (float)pp.y + biasB, aB1 = 0.f;
    const uint4* h4 = (const uint4*)lds_h;
    #pragma unroll
    for (int k = 0; k < 16; k++){
      uint4 hv = h4[k];
      h2v p0 = bch2(hv.x), p1 = bch2(hv.y), p2 = bch2(hv.z), p3 = bch2(hv.w);
      aA0 = fdot2(whA[4 * k + 0], p0, aA0);
      aA1 = fdot2(whA[4 * k + 1], p1, aA1);
      aA0 = fdot2(whA[4 * k + 2], p2, aA0);
      aA1 = fdot2(whA[4 * k + 3], p3, aA1);
      aB0 = fdot2(whB[4 * k + 0], p0, aB0);
      aB1 = fdot2(whB[4 * k + 1], p1, aB1);
      aB0 = fdot2(whB[4 * k + 2], p2, aB0);
      aB1 = fdot2(whB[4 * k + 3], p3, aB1);
    }
    float2 gw; gw.x = aA0 + aA1; gw.y = aB0 + aB1;
    ((float2*)lds_g)[tid] = gw;
    __syncthreads();                       // gates ready; lds_h reads done

    if (tid < 128){
      float gi = lds_g[tid], gf = lds_g[tid + 128], gg = lds_g[tid + 256], go = lds_g[tid + 384];
      c = sigm(gf) * c + sigm(gi) * tanhfast(gg);
      float hv2 = sigm(go) * tanhfast(c);
      ((__fp16*)lds_h)[tid] = (__fp16)hv2;
      hlast = hv2;
      if (hout) hout[((size_t)n * TSEQ + t0 + t) * 128 + tid] = bf16rne(hv2);
    }
    __syncthreads();                       // lds_h ready for next step
    pv = pvn;
  }
  if (tid < 64) h_state[n * 64 + tid] = lds_h[tid];
  if (tid < 128){
    c_state[n * 128 + tid] = c;
    if (pout) pout[n * 128 + tid] = leakyf(hlast);
  }
}

// ---------------- H1: per-node MLP up to n ----------------
__global__ void node_mlp(
    const float* __restrict__ x_tag, const float* __restrict__ pm,
    const float* __restrict__ Wvm, const float* __restrict__ Wup,
    const float* __restrict__ W_hyb, const float* __restrict__ b_hyb,
    const float* __restrict__ W_act, const float* __restrict__ b_act,
    const float* __restrict__ W_inact, const float* __restrict__ b_inact,
    const float* __restrict__ p, float* __restrict__ nmat)
{
  int n = blockIdx.x, tid = threadIdx.x;
  __shared__ float pl[128], up[128], vm[128], hh[256];
  float act = x_tag[n * 3 + 2], hp0 = x_tag[n * 3 + 0], hp1 = x_tag[n * 3 + 1];
  if (tid < 128) pl[tid] = p[n * 128 + tid];
  __syncthreads();
  if (tid < 128){
    float a1 = 0.f;
    for (int k = 0; k < 768; k++) a1 += pm[k] * Wvm[k * 128 + tid];
    a1 += act * Wvm[768 * 128 + tid];
    vm[tid] = leakyf(a1);
    float a2 = 0.f;
    for (int k = 0; k < 128; k++) a2 += pl[k] * Wup[k * 128 + tid];
    up[tid] = leakyf(a2);
  }
  __syncthreads();
  {
    float a = b_hyb[tid];
    for (int k = 0; k < 128; k++) a += up[k] * W_hyb[k * 256 + tid];
    for (int k = 0; k < 128; k++) a += (up[k] + vm[k]) * W_hyb[(128 + k) * 256 + tid];
    for (int k = 0; k < 128; k++) a += vm[k] * W_hyb[(256 + k) * 256 + tid];
    hh[tid] = leakyf(a);
  }
  __syncthreads();
  {
    float na = b_act[tid];
    for (int k = 0; k < 256; k++) na += hh[k] * W_act[k * 256 + tid];
    na += hp0 * W_act[256 * 256 + tid] + hp1 * W_act[257 * 256 + tid];
    float ni = b_inact[tid];
    for (int k = 0; k < 256; k++) ni += hh[k] * W_inact[k * 256 + tid];
    nmat[n * 256 + tid] = leakyf(na * (1.f - act) + ni * act);
  }
}

// ---------------- H2: per-node projections of n ----------------
__global__ void node_proj(
    const float* __restrict__ nmat,
    const float* __restrict__ Wphin, const float* __restrict__ Won,
    const float* __restrict__ Weo,
    float* __restrict__ A, float* __restrict__ B,
    float* __restrict__ C, float* __restrict__ D,
    float* __restrict__ Q, float* __restrict__ R)
{
  int n = blockIdx.x, tid = threadIdx.x;
  __shared__ float nl[256];
  nl[tid] = nmat[n * 256 + tid];
  __syncthreads();
  if (tid < 192){
    float a = 0.f, b = 0.f;
    for (int k = 0; k < 256; k++){ float v = nl[k]; a += v * Wphin[k * 192 + tid]; b += v * Wphin[(256 + k) * 192 + tid]; }
    A[n * 192 + tid] = a; B[n * 192 + tid] = b;
  }
  float c = 0.f, d = 0.f, q = 0.f, r = 0.f;
  for (int k = 0; k < 256; k++){
    float v = nl[k];
    c += v * Won[k * 256 + tid];
    d += v * Won[(256 + k) * 256 + tid];
    q += v * Weo[(256 + k) * 256 + tid];
    r += v * Weo[(512 + k) * 256 + tid];
  }
  C[n * 256 + tid] = c; D[n * 256 + tid] = d;
  Q[n * 256 + tid] = q; R[n * 256 + tid] = r;
}

// ---------------- H3: phi ----------------
__global__ void phi_kernel(const float* __restrict__ A, const float* __restrict__ B,
                           const float* __restrict__ aphi, float* __restrict__ phiT)
{
  int j = blockIdx.x, tid = threadIdx.x;
  __shared__ float Aj[192], ap[192];
  for (int k = tid; k < 192; k += 128){ Aj[k] = A[j * 192 + k]; ap[k] = aphi[k]; }
  __syncthreads();
  if (tid < NNODE){
    const float* Bi = B + (size_t)tid * 192;
    float s = 0.f;
    for (int k = 0; k < 192; k++) s += leakyf(Aj[k] + Bi[k]) * ap[k];
    phiT[j * NNODE + tid] = s;
  }
}

// ---------------- H4: masked softmaxes ----------------
__global__ void alpha_kernel(const float* __restrict__ phiT, const float* __restrict__ x_tag,
                             float* __restrict__ alpha)
{
  int j = blockIdx.x, tid = threadIdx.x;
  __shared__ float buf[128];
  bool valid = tid < NNODE;
  float ph = valid ? phiT[j * NNODE + tid] : 0.f;
  float a  = valid ? x_tag[tid * 3 + 2] : -1.f;
  bool v1 = (a == 0.f), v0 = (a == 1.f);

  float c1 = bred_sum((valid && v1) ? 1.f : 0.f, buf, 128);

  float x1 = (valid && v1) ? ph : NEGC;
  float m1 = bred_max(valid ? x1 : -3.4e38f, buf, 128);
  float e1 = valid ? __expf(x1 - m1) : 0.f;
  float s1 = bred_sum(e1, buf, 128);
  float p1 = e1 / s1;

  float x0 = (valid && v0) ? ph : NEGC;
  float m0 = bred_max(valid ? x0 : -3.4e38f, buf, 128);
  float e0 = valid ? __expf(x0 - m0) : 0.f;
  float s0 = bred_sum(e0, buf, 128);
  float p0 = e0 / s0;

  float ma = bred_max(valid ? ph : -3.4e38f, buf, 128);
  float ea = valid ? __expf(ph - ma) : 0.f;
  float sa = bred_sum(ea, buf, 128);
  float pa = ea / sa;

  float pmask = v1 ? p1 : (v0 ? p0 : ph);
  float al = (c1 > 0.f) ? pmask : pa;
  if (valid) alpha[tid * NNODE + j] = al;
}

// ---------------- H5: alpha-weighted sums ----------------
__global__ void att_sum(const float* __restrict__ alpha, const float* __restrict__ C,
                        const float* __restrict__ D, const float* __restrict__ Q,
                        const float* __restrict__ R, const float* __restrict__ nmat,
                        float* __restrict__ T1, float* __restrict__ Spart,
                        float* __restrict__ nrm)
{
  int i = blockIdx.x, tid = threadIdx.x;
  __shared__ float al[128];
  __shared__ float rb[256];
  if (tid < 128) al[tid] = (tid < NNODE) ? alpha[i * NNODE + tid] : 0.f;
  __syncthreads();
  float Di = D[i * 256 + tid];
  float acc1 = 0.f, acc2 = 0.f, sa = 0.f;
  for (int jj = 0; jj < NNODE; jj++){
    float av = al[jj]; sa += av;
    acc1 += av * leakyf(C[jj * 256 + tid] + Di);
    acc2 += av * Q[jj * 256 + tid];
  }
  T1[i * 256 + tid] = acc1;
  Spart[i * 256 + tid] = acc2 + sa * R[i * 256 + tid];
  float nv = nmat[i * 256 + tid];
  float ss = bred_sum(nv * nv, rb, 256);
  if (tid == 0) nrm[i] = fmaxf(sqrtf(ss), 1e-8f);
}

// ---------------- H6: per-node finalize ----------------
__global__ void finalize_node(const float* __restrict__ T1, const float* __restrict__ Spart,
                              const float* __restrict__ Weo, const float* __restrict__ nmat,
                              const float* __restrict__ x_tag, const float* __restrict__ Wi,
                              const float* __restrict__ bi, const float* __restrict__ nrm,
                              float* __restrict__ vvec, float* __restrict__ out)
{
  int i = blockIdx.x, tid = threadIdx.x;
  __shared__ float t1[256];
  __shared__ float rb[256];
  t1[tid] = T1[i * 256 + tid];
  __syncthreads();
  float s = Spart[i * 256 + tid];
  for (int k = 0; k < 256; k++) s += t1[k] * Weo[k * 256 + tid];
  float act = x_tag[i * 3 + 2], hp0 = x_tag[i * 3 + 0], hp1 = x_tag[i * 3 + 1];
  float hm0 = leakyf(act * s);
  float hm1 = leakyf((1.f - act) * s);
  float nd = nmat[i * 256 + tid];
  const float* Wir = Wi + (size_t)i * 1536;
  float y0 = nd * Wir[tid * 2]     + hm0 * Wir[(256 + tid) * 2]     + hm1 * Wir[(512 + tid) * 2];
  float y1 = nd * Wir[tid * 2 + 1] + hm0 * Wir[(256 + tid) * 2 + 1] + hm1 * Wir[(512 + tid) * 2 + 1];
  y0 = bred_sum(y0, rb, 256);
  y1 = bred_sum(y1, rb, 256);
  float sgn = (hp1 > hp0) ? 1.f : ((hp1 < hp0) ? -1.f : 0.f);
  if (act == 0.f && sgn != 0.f) atomicAdd(vvec + tid, sgn * nd / nrm[i]);
  if (tid == 0){
    y0 += bi[i * 2]; y1 += bi[i * 2 + 1];
    float m = fmaxf(y0, y1);
    float ee0 = __expf(y0 - m), ee1 = __expf(y1 - m);
    float ssum = ee0 + ee1;
    out[i * 2]     = ee0 / ssum;
    out[i * 2 + 1] = ee1 / ssum;
    out[236 + i * 2]     = hp0;
    out[236 + i * 2 + 1] = hp1;
    out[474 + i] = (act == 0.f) ? 1.f : 0.f;
    out[592 + i] = (act == 1.f) ? 1.f : 0.f;
  }
}

// ---------------- H_ort ----------------
__global__ void ort_kernel(const float* __restrict__ Wum, const float* __restrict__ Wvm,
                           const float* __restrict__ Wup, const float* __restrict__ Wvp,
                           float* __restrict__ misc)
{
  int a = blockIdx.x, b = threadIdx.x;
  float g1 = 0.f, g2 = 0.f, g3 = 0.f, g4 = 0.f;
  for (int r = 0; r < 769; r++){
    g1 += Wum[r * 128 + a] * Wum[r * 128 + b];
    g2 += Wvm[r * 128 + a] * Wvm[r * 128 + b];
  }
  for (int r = 0; r < 128; r++){
    g3 += Wup[r * 128 + a] * Wup[r * 128 + b];
    g4 += Wvp[r * 128 + a] * Wvp[r * 128 + b];
  }
  __shared__ float rb[128];
  float s1 = bred_sum(g1 * g2, rb, 128);
  float s2 = bred_sum(g3 * g4, rb, 128);
  if (b == 0){ atomicAdd(misc + 0, s1); atomicAdd(misc + 1, s2); }
}

// ---------------- H7: scalars ----------------
__global__ void finalize_scalars(const float* __restrict__ misc, const float* __restrict__ vvec,
                                 float* __restrict__ out)
{
  __shared__ float rb[256];
  int tid = threadIdx.x;
  float v = vvec[tid];
  float ss = bred_sum(v * v, rb, 256);
  if (tid == 0){
    out[472] = sqrtf(misc[0]) + sqrtf(misc[1]);
    out[473] = ss;
  }
}

extern "C" void kernel_launch(void* const* d_in, const int* in_sizes, int n_in,
                              void* d_out, int out_size, void* d_ws, size_t ws_size,
                              hipStream_t stream)
{
  const float* x        = (const float*)d_in[0];
  const float* x_tag    = (const float*)d_in[1];
  const float* W_ih0    = (const float*)d_in[2];
  const float* W_hh0    = (const float*)d_in[3];
  const float* b_ih0    = (const float*)d_in[4];
  const float* b_hh0    = (const float*)d_in[5];
  const float* W_ih1    = (const float*)d_in[6];
  const float* W_hh1    = (const float*)d_in[7];
  const float* b_ih1    = (const float*)d_in[8];
  const float* b_hh1    = (const float*)d_in[9];
  const float* pm       = (const float*)d_in[10];
  const float* Wum      = (const float*)d_in[11];
  const float* Wvm      = (const float*)d_in[12];
  const float* Wup      = (const float*)d_in[13];
  const float* Wvp      = (const float*)d_in[14];
  const float* W_hyb    = (const float*)d_in[15];
  const float* b_hyb    = (const float*)d_in[16];
  const float* W_act    = (const float*)d_in[17];
  const float* b_act    = (const float*)d_in[18];
  const float* W_inact  = (const float*)d_in[19];
  const float* b_inact  = (const float*)d_in[20];
  const float* Wphin    = (const float*)d_in[21];
  const float* aphi     = (const float*)d_in[22];
  const float* Won      = (const float*)d_in[23];
  const float* Weo      = (const float*)d_in[24];
  const float* Wi       = (const float*)d_in[25];
  const float* bi       = (const float*)d_in[26];
  float* out = (float*)d_out;

  char* base = (char*)d_ws;
  size_t off = 0;
  auto take = [&](size_t bytes) -> char* {
    char* p = base + off;
    off += (bytes + 255) & ~(size_t)255;
    return p;
  };
  __fp16* pre          = (__fp16*)take((size_t)NNODE * TC * 512 * 2);        // ~29.5MB
  unsigned short* h1bf = (unsigned short*)take((size_t)NNODE * TSEQ * 128 * 2); // ~59MB
  unsigned short* wf0  = (unsigned short*)take((size_t)512 * 128 * 2);
  unsigned short* wf1  = (unsigned short*)take((size_t)512 * 128 * 2);
  unsigned int* hstate = (unsigned int*)take((size_t)NNODE * 64 * 4);
  float* cstate        = (float*)take((size_t)NNODE * 128 * 4);
  float* pbuf  = (float*)take((size_t)NNODE * 128 * 4);
  float* nmat  = (float*)take((size_t)NNODE * 256 * 4);
  float* Amat  = (float*)take((size_t)NNODE * 192 * 4);
  float* Bmat  = (float*)take((size_t)NNODE * 192 * 4);
  float* Cmat  = (float*)take((size_t)NNODE * 256 * 4);
  float* Dmat  = (float*)take((size_t)NNODE * 256 * 4);
  float* Qmat  = (float*)take((size_t)NNODE * 256 * 4);
  float* Rmat  = (float*)take((size_t)NNODE * 256 * 4);
  float* phiT  = (float*)take((size_t)NNODE * NNODE * 4);
  float* alpha = (float*)take((size_t)NNODE * NNODE * 4);
  float* T1    = (float*)take((size_t)NNODE * 256 * 4);
  float* Spart = (float*)take((size_t)NNODE * 256 * 4);
  float* nrm   = (float*)take((size_t)NNODE * 4);
  float* vvec  = (float*)take(256 * 4);
  float* misc  = (float*)take(8 * 4);

  hipMemsetAsync(vvec, 0, 1024 + 32, stream);

  // W_ih -> bf16
  f32_to_bf16_k<<<256, 256, 0, stream>>>(W_ih0, wf0, 512 * 128);
  f32_to_bf16_k<<<256, 256, 0, stream>>>(W_ih1, wf1, 512 * 128);

  // Layer 1: chunked GEMM + scan (writes h1 sequence as bf16)
  for (int c = 0; c < NCH; c++){
    pregemm<<<NNODE * 4, 256, 0, stream>>>((const void*)x, 1, wf0, pre, c * TC);
    lstm_scan_pre<<<NNODE, 256, 0, stream>>>(pre, W_hh0, b_ih0, b_hh0,
                                             h1bf, nullptr, hstate, cstate, c * TC);
  }
  // Layer 2: chunked GEMM (A = h1 bf16) + scan (writes p on last chunk)
  for (int c = 0; c < NCH; c++){
    pregemm<<<NNODE * 4, 256, 0, stream>>>((const void*)h1bf, 0, wf1, pre, c * TC);
    lstm_scan_pre<<<NNODE, 256, 0, stream>>>(pre, W_hh1, b_ih1, b_hh1,
                                             nullptr, (c == NCH - 1) ? pbuf : nullptr,
                                             hstate, cstate, c * TC);
  }

  node_mlp<<<NNODE, 256, 0, stream>>>(x_tag, pm, Wvm, Wup, W_hyb, b_hyb,
                                      W_act, b_act, W_inact, b_inact, pbuf, nmat);
  node_proj<<<NNODE, 256, 0, stream>>>(nmat, Wphin, Won, Weo, Amat, Bmat, Cmat, Dmat, Qmat, Rmat);
  phi_kernel<<<NNODE, 128, 0, stream>>>(Amat, Bmat, aphi, phiT);
  alpha_kernel<<<NNODE, 128, 0, stream>>>(phiT, x_tag, alpha);
  att_sum<<<NNODE, 256, 0, stream>>>(alpha, Cmat, Dmat, Qmat, Rmat, nmat, T1, Spart, nrm);
  finalize_node<<<NNODE, 256, 0, stream>>>(T1, Spart, Weo, nmat, x_tag, Wi, bi, nrm, vvec, out);
  ort_kernel<<<128, 128, 0, stream>>>(Wum, Wvm, Wup, Wvp, misc);
  finalize_scalars<<<1, 256, 0, stream>>>(misc, vvec, out);
}